// Round 3
// baseline (226.648 us; speedup 1.0000x reference)
//
#include <hip/hip_runtime.h>
#include <hip/hip_bf16.h>

typedef __attribute__((ext_vector_type(8))) __bf16 bf16x8;
typedef __attribute__((ext_vector_type(8))) short short8;
typedef __attribute__((ext_vector_type(4))) float f32x4;
typedef __attribute__((ext_vector_type(16))) float f32x16;
typedef __attribute__((ext_vector_type(4))) short sh4;

typedef __attribute__((address_space(1))) void GVoid;
typedef __attribute__((address_space(3))) void LVoid;

#define NEGBIG (-1e30f)
#define SCL 0.18033688011112042f   // 0.125 * log2(e): folded into Q at GEMM1 epilogue

constexpr int TT = 2048, CC = 1024, HH = 16, DD = 64, C3 = 3072;
constexpr int NTASK = 512;         // 16 q-tiles x 32 bh

__device__ __forceinline__ unsigned short f2bf(float f) {   // RNE
  unsigned int i = __float_as_uint(f);
  return (unsigned short)((i + 0x7FFFu + ((i >> 16) & 1u)) >> 16);
}
__device__ __forceinline__ void async16(const void* g, void* l) {
  __builtin_amdgcn_global_load_lds((GVoid*)g, (LVoid*)l, 16, 0, 0);
}

// ---------- pre-pass: fp32 -> bf16 elementwise convert ----------
__global__ __launch_bounds__(256) void cvt_bf16(
    const float* __restrict__ in, unsigned short* __restrict__ out, int n8)
{
  const int i = blockIdx.x * 256 + threadIdx.x;
  if (i >= n8) return;
  const float* p = in + (size_t)i * 8;
  f32x4 a = *(const f32x4*)p, b = *(const f32x4*)(p + 4);
  sh4 r0, r1;
  ((unsigned short*)&r0)[0] = f2bf(a[0]); ((unsigned short*)&r0)[1] = f2bf(a[1]);
  ((unsigned short*)&r0)[2] = f2bf(a[2]); ((unsigned short*)&r0)[3] = f2bf(a[3]);
  ((unsigned short*)&r1)[0] = f2bf(b[0]); ((unsigned short*)&r1)[1] = f2bf(b[1]);
  ((unsigned short*)&r1)[2] = f2bf(b[2]); ((unsigned short*)&r1)[3] = f2bf(b[3]);
  *(sh4*)(out + (size_t)i * 8) = r0;
  *(sh4*)(out + (size_t)i * 8 + 4) = r1;
}

// ---------- pre-pass: transpose + convert: fp32 in[R][Cd] -> bf16 out[Cd][R] ----------
__global__ __launch_bounds__(256) void transpose_cvt(
    const float* __restrict__ in, unsigned short* __restrict__ out, int R, int Cd)
{
  __shared__ __align__(16) unsigned short tile[64 * 72];
  const int r0 = blockIdx.y * 64, c0 = blockIdx.x * 64;
  const int tid = threadIdx.x;
#pragma unroll
  for (int r = 0; r < 2; ++r) {
    const int elem = r * 2048 + tid * 8;
    const int ii = elem >> 6, jj = elem & 63;
    const float* p = in + (size_t)(r0 + ii) * Cd + c0 + jj;
    f32x4 a = *(const f32x4*)p, b = *(const f32x4*)(p + 4);
    short8 v;
    ((unsigned short*)&v)[0] = f2bf(a[0]); ((unsigned short*)&v)[1] = f2bf(a[1]);
    ((unsigned short*)&v)[2] = f2bf(a[2]); ((unsigned short*)&v)[3] = f2bf(a[3]);
    ((unsigned short*)&v)[4] = f2bf(b[0]); ((unsigned short*)&v)[5] = f2bf(b[1]);
    ((unsigned short*)&v)[6] = f2bf(b[2]); ((unsigned short*)&v)[7] = f2bf(b[3]);
    *(short8*)&tile[ii * 72 + jj] = v;
  }
  __syncthreads();
#pragma unroll
  for (int r = 0; r < 2; ++r) {
    const int elem = r * 2048 + tid * 8;
    const int jj = elem >> 6, ii0 = elem & 63;
    short8 v;
#pragma unroll
    for (int e = 0; e < 8; ++e) ((unsigned short*)&v)[e] = tile[(ii0 + e) * 72 + jj];
    *(short8*)&out[(size_t)(c0 + jj) * R + r0 + ii0] = v;
  }
}

// ---------------- GEMM (m97 structure) ----------------
template <int MODE>
__global__ __launch_bounds__(256) void gemm_bt(
    const unsigned short* __restrict__ A,
    const unsigned short* __restrict__ Bt,
    const float* __restrict__ bias,
    void* __restrict__ Cp, unsigned short* __restrict__ Vt,
    int M, int N, int K, int lda)
{
  __shared__ __align__(16) unsigned short sA[128 * 32];
  __shared__ __align__(16) unsigned short sB[128 * 32];
  const int tid = threadIdx.x;
  const int w = tid >> 6, l = tid & 63, ln = l & 15, quad = l >> 4;
  const int wm = w >> 1, wn = w & 1;
  const int m0 = blockIdx.y * 128, n0 = blockIdx.x * 128;
  f32x4 acc[4][4] = {};

  for (int k0 = 0; k0 < K; k0 += 32) {
    __syncthreads();
#pragma unroll
    for (int r = 0; r < 2; ++r) {
      const int elem = r * 2048 + tid * 8;
      const int ar = elem >> 5, ac = elem & 31;
      async16(A  + (size_t)(m0 + ar) * lda + k0 + ac, sA + r * 2048 + w * 512);
      async16(Bt + (size_t)(n0 + ar) * K   + k0 + ac, sB + r * 2048 + w * 512);
    }
    __syncthreads();

    bf16x8 af[4], bfr[4];
#pragma unroll
    for (int i = 0; i < 4; i++)
      af[i] = *(const bf16x8*)&sA[(wm * 64 + i * 16 + ln) * 32 + quad * 8];
#pragma unroll
    for (int j = 0; j < 4; j++)
      bfr[j] = *(const bf16x8*)&sB[(wn * 64 + j * 16 + ln) * 32 + quad * 8];
#pragma unroll
    for (int i = 0; i < 4; i++)
#pragma unroll
      for (int j = 0; j < 4; j++)
        acc[i][j] = __builtin_amdgcn_mfma_f32_16x16x32_bf16(af[i], bfr[j], acc[i][j], 0, 0, 0);
  }

  float bj[4];
#pragma unroll
  for (int j = 0; j < 4; j++) bj[j] = bias[n0 + wn * 64 + j * 16 + ln];

#pragma unroll
  for (int i = 0; i < 4; i++)
#pragma unroll
    for (int g = 0; g < 4; ++g) {
      const int gm = m0 + wm * 64 + i * 16 + quad * 4 + g;
#pragma unroll
      for (int j = 0; j < 4; j++) {
        const int gn = n0 + wn * 64 + j * 16 + ln;
        float v = acc[i][j][g] + bj[j];
        if (MODE == 0) {
          if (gn < 2048) {
            if (gn < 1024) v *= SCL;       // fold softmax scale into Q (pre-round: free)
            ((unsigned short*)Cp)[(size_t)gm * 2048 + gn] = f2bf(v);
          } else {
            const int hh = (gn >> 6) & 15, dd = gn & 63;
            const int bb = gm >> 11, t = gm & 2047;
            Vt[((size_t)((bb * HH + hh) * DD + dd)) * TT + t] = f2bf(v);
          }
        } else {
          ((float*)Cp)[(size_t)gm * N + gn] = v;
        }
      }
    }
}

// ---------------- Flash attention (causal), D=64 ----------------
// 4 waves x 32 q-rows = 128-row q-tiles. Dynamic LPT task queue: 512 tasks
// (qt descending x 32 bh) pulled via global atomic -> load balance independent
// of block placement; 46KB LDS -> 2-3 blocks/CU, independent barrier domains.
// LDS-traffic-minimized iteration (prior version was LDS-pipe-bound):
//  * 32x32x16 MFMA: K/V-tile read ONCE per wave serves 32 q-rows (2x fewer
//    ds_read_b128 per q-row than 16x16x32).
//  * S^T = mfma(K,Q): lane holds P-column for q=lane&31; P->PV A-fragment built
//    IN-REGISTER via v_cvt_pk_bf16_f32 + v_permlane32_swap_b32 (T12): the entire
//    pt LDS round-trip (128 b16 writes + 16 b128 reads per CU-iter) is gone.
//  * l = per-lane scalar sum + shfl_xor(32); normalize via epilogue bpermute.
// STATIC softmax (scores bounded, Q pre-scaled by GEMM1, log2 domain).
// PV lags QK by one k-tile (P in regs across barrier); vt triple-buffered.
__global__ __launch_bounds__(256) void attn32x32(
    unsigned short* __restrict__ QK, const unsigned short* __restrict__ Vt,
    unsigned int* __restrict__ cnt)
{
  __shared__ __align__(16) unsigned short kt[2][64 * 72];   // [key][d]
  __shared__ __align__(16) unsigned short vt[3][64 * 72];   // [d][key] rotating
  __shared__ int sh_task;
  const int tid = threadIdx.x, w = tid >> 6, l = tid & 63;
  const int c = l & 31, h2 = l >> 5;                        // col / half within wave
  const int si0 = tid >> 3, so = (tid & 7) * 8;             // staging: 32x64 per pass

  for (;;) {
    if (tid == 0) sh_task = (int)atomicAdd(cnt, 1u);
    __syncthreads();                                        // also fences prior task's LDS reads
    const int task = sh_task;
    if (task >= NTASK) return;
    const int qt = 15 - (task >> 5);                        // longest first (LPT)
    const int bh = task & 31;
    const int b = bh >> 4, h = bh & 15;
    unsigned short*       Qp = QK + (size_t)b * TT * 2048 + h * DD;
    const unsigned short* Kp = QK + (size_t)b * TT * 2048 + CC + h * DD;
    const unsigned short* Vh = Vt + (size_t)bh * DD * TT;

    const int qbase = qt * 128 + w * 32;                    // wave's first q-row
    const int qm = qbase + c - 4 * h2;                      // mask helper
    bf16x8 qv[4];
#pragma unroll
    for (int ds = 0; ds < 4; ++ds)                          // Q B-operand frags (regs)
      qv[ds] = *(const bf16x8*)&Qp[(size_t)(qbase + c) * 2048 + ds * 16 + h2 * 8];

    f32x16 oacc[2] = {};
    bf16x8 pA[4] = {};
    float lsum = 0.0f;
    const int kbmax = 2 * qt + 1;
    int vm1 = 2, v0 = 0, vp1 = 1;                           // (kb-1,kb,kb+1) % 3

    // stage kb=0 into buffer 0
#pragma unroll
    for (int r = 0; r < 2; ++r) {
      const int si = si0 + 32 * r;
      *(short8*)&kt[0][si * 72 + so] = *(const short8*)&Kp[(size_t)si * 2048 + so];
      *(short8*)&vt[0][si * 72 + so] = *(const short8*)&Vh[(size_t)si * TT + so];
    }
    __syncthreads();

    for (int kb = 0; kb <= kbmax; ++kb) {
      const int ck = kb & 1;
      short8 pk[2], pv[2];
      if (kb < kbmax) {                                     // prefetch kb+1 -> regs
#pragma unroll
        for (int r = 0; r < 2; ++r) {
          const int si = si0 + 32 * r;
          pk[r] = *(const short8*)&Kp[(size_t)((kb + 1) * 64 + si) * 2048 + so];
          pv[r] = *(const short8*)&Vh[(size_t)si * TT + (kb + 1) * 64 + so];
        }
      }
      const bool qk_act = (kb * 64 <= qbase + 31);          // wave-uniform
      f32x16 sacc[2];
      if (qk_act) {                                         // S^T(kb) = K * Q^T
#pragma unroll
        for (int kg = 0; kg < 2; ++kg) {
          f32x16 sa = {};
#pragma unroll
          for (int ds = 0; ds < 4; ++ds) {
            bf16x8 kf = *(const bf16x8*)&kt[ck][(kg * 32 + c) * 72 + ds * 16 + h2 * 8];
            sa = __builtin_amdgcn_mfma_f32_32x32x16_bf16(kf, qv[ds], sa, 0, 0, 0);
          }
          sacc[kg] = sa;
        }
      }
      if (kb > 0 && (kb - 1) * 64 <= qbase + 31) {          // PV(kb-1): independent,
        const unsigned short* vp = vt[vm1];                 // overlaps exp2 chain
#pragma unroll
        for (int dg = 0; dg < 2; ++dg)
#pragma unroll
          for (int ks = 0; ks < 4; ++ks) {
            bf16x8 vf = *(const bf16x8*)&vp[(dg * 32 + c) * 72 + ks * 16 + h2 * 8];
            oacc[dg] = __builtin_amdgcn_mfma_f32_32x32x16_bf16(pA[ks], vf, oacc[dg], 0, 0, 0);
          }
      }
      if (qk_act) {
        const bool need_mask = (kb * 64 + 63 > qbase);
        float pe[2][16];
#pragma unroll
        for (int kg = 0; kg < 2; ++kg)
#pragma unroll
          for (int r = 0; r < 16; ++r) {
            float s = sacc[kg][r];
            if (need_mask) {
              const int krel = kb * 64 + kg * 32 + (r & 3) + 8 * (r >> 2); // + 4*h2 vs qm
              if (krel > qm) s = NEGBIG;                    // key > q  -> masked
            }
            const float e = exp2f(s);
            pe[kg][r] = e;
            lsum += e;
          }
        // pack P^T pairs to bf16 (RNE) and redistribute to PV A-fragments
        unsigned W0[2][4], W1[2][4];
#pragma unroll
        for (int kg = 0; kg < 2; ++kg)
#pragma unroll
          for (int r = 0; r < 4; ++r) {
            asm("v_cvt_pk_bf16_f32 %0, %1, %2"
                : "=v"(W0[kg][r]) : "v"(pe[kg][4 * r + 0]), "v"(pe[kg][4 * r + 1]));
            asm("v_cvt_pk_bf16_f32 %0, %1, %2"
                : "=v"(W1[kg][r]) : "v"(pe[kg][4 * r + 2]), "v"(pe[kg][4 * r + 3]));
          }
#pragma unroll
        for (int ks = 0; ks < 4; ++ks) {
          const int kg = ks >> 1, sel = ks & 1;
          unsigned a0 = W0[kg][2 * sel], b0 = W0[kg][2 * sel + 1];
          unsigned a1 = W1[kg][2 * sel], b1 = W1[kg][2 * sel + 1];
          asm("v_permlane32_swap_b32 %0, %1" : "+v"(a0), "+v"(b0));
          asm("v_permlane32_swap_b32 %0, %1" : "+v"(a1), "+v"(b1));
          unsigned wds[4] = {a0, a1, b0, b1};               // keys e01,e23,e45,e67
          pA[ks] = *(const bf16x8*)wds;
        }
      }
      if (kb < kbmax) {                                     // stage kb+1
#pragma unroll
        for (int r = 0; r < 2; ++r) {
          const int si = si0 + 32 * r;
          *(short8*)&kt[1 - ck][si * 72 + so] = pk[r];
          *(short8*)&vt[vp1][si * 72 + so] = pv[r];
        }
      }
      __syncthreads();                                      // one barrier per iter
      const int t_ = vm1; vm1 = v0; v0 = vp1; vp1 = t_;     // rotate V buffers
    }
    // drain: PV(kbmax) for waves whose last k-tile is kbmax (upper 64 rows)
    if (kbmax * 64 <= qbase + 31) {
      const unsigned short* vp = vt[vm1];                   // vm1 == kbmax % 3
#pragma unroll
      for (int dg = 0; dg < 2; ++dg)
#pragma unroll
        for (int ks = 0; ks < 4; ++ks) {
          bf16x8 vf = *(const bf16x8*)&vp[(dg * 32 + c) * 72 + ks * 16 + h2 * 8];
          oacc[dg] = __builtin_amdgcn_mfma_f32_32x32x16_bf16(pA[ks], vf, oacc[dg], 0, 0, 0);
        }
    }
    // epilogue: l across halves, normalize, store O (in place of Q)
    lsum += __shfl_xor(lsum, 32);
    const float inv = 1.0f / lsum;                          // valid for q=c, all lanes
#pragma unroll
    for (int r = 0; r < 16; ++r) {
      const int q_rel = (r & 3) + 8 * (r >> 2) + 4 * h2;
      const float iq = __shfl(inv, q_rel);
      const size_t trow = qbase + q_rel;
#pragma unroll
      for (int dg = 0; dg < 2; ++dg)
        Qp[trow * 2048 + dg * 32 + c] = f2bf(oacc[dg][r] * iq);
    }
  }
}

extern "C" void kernel_launch(void* const* d_in, const int* in_sizes, int n_in,
                              void* d_out, int out_size, void* d_ws, size_t ws_size,
                              hipStream_t stream)
{
  (void)in_sizes; (void)n_in; (void)out_size; (void)ws_size;
  const float* x     = (const float*)d_in[0];   // [B,T,C] fp32
  const float* Wqkv  = (const float*)d_in[1];   // [C,3C]
  const float* bqkv  = (const float*)d_in[2];   // [3C]
  const float* Wproj = (const float*)d_in[3];   // [C,C]
  const float* bproj = (const float*)d_in[4];   // [C]

  unsigned short* QK     = (unsigned short*)d_ws;            // [4096][2048] bf16, 16 MB
  unsigned short* WqkvT  = QK + (size_t)4096 * 2048;         // [3072][1024] bf16, 6 MB
  unsigned short* WprojT = WqkvT;                            // aliases (after GEMM1)
  // task counter: lives in the WqkvT region beyond the 2MB WprojT alias --
  // dead after GEMM1 has consumed WqkvT, untouched by transpose_cvt(Wproj).
  unsigned int* cnt = (unsigned int*)(WqkvT + 3000000);
  unsigned short* Vt = (unsigned short*)d_out;               // scratch in d_out, 8 MB
  unsigned short* xb = Vt + (size_t)32 * 64 * 2048;          // scratch in d_out, 8 MB

  cvt_bf16<<<dim3(4096 * 1024 / 8 / 256), 256, 0, stream>>>(x, xb, 4096 * 1024 / 8);
  transpose_cvt<<<dim3(C3 / 64, CC / 64), 256, 0, stream>>>(Wqkv, WqkvT, CC, C3);
  gemm_bt<0><<<dim3(C3 / 128, 4096 / 128), 256, 0, stream>>>(
      xb, WqkvT, bqkv, QK, Vt, 4096, C3, CC, CC);
  transpose_cvt<<<dim3(CC / 64, CC / 64), 256, 0, stream>>>(Wproj, WprojT, CC, CC);
  hipMemsetAsync(cnt, 0, 4, stream);
  attn32x32<<<dim3(NTASK), 256, 0, stream>>>(QK, Vt, cnt);
  gemm_bt<1><<<dim3(CC / 128, 4096 / 128), 256, 0, stream>>>(
      QK, WprojT, bproj, d_out, nullptr, 4096, CC, CC, 2048);
}